// Round 8
// baseline (176.368 us; speedup 1.0000x reference)
//
#include <hip/hip_runtime.h>

typedef unsigned int   u32;
typedef unsigned short u16;
typedef __attribute__((ext_vector_type(8))) short bf16x8;
typedef __attribute__((ext_vector_type(4))) float f32x4;

// ---------- bf16 helpers ----------
__device__ __forceinline__ float bfs(u16 u) {
  union { u32 i; float f; } v; v.i = ((u32)u) << 16; return v.f;
}
__device__ __forceinline__ u16 f2bf(float f) {
  union { float f; u32 i; } v; v.f = f;
  u32 r = v.i + 0x7fffu + ((v.i >> 16) & 1u);   // RNE
  return (u16)(r >> 16);
}
__device__ __forceinline__ ushort4 f2bf4(float4 v) {
  ushort4 p; p.x = f2bf(v.x); p.y = f2bf(v.y); p.z = f2bf(v.z); p.w = f2bf(v.w);
  return p;
}

// ============ single kernel: proj + lookback-Hpre + ssm + out-GEMM =========
// grid (tt=32, h=16), 256 threads (4 waves). LDS 47104 B, VGPR<256 ->
// >=2 blocks/CU -> all 512 blocks co-resident -> flag chains cannot deadlock.
// Sync protocol (proven in r6/r7): writers publish with agent-scope atomic
// stores (reach the coherence point), __syncthreads drains vmcnt, tid0 does a
// release/ACQ_REL flag op; readers acquire-poll the flag, then PLAIN loads
// are safe (first touch of each line is post-flag within this launch).
//   - G/dec -> flags[bh*16+it]   (per-bh lookback chain, 16 deep)
//   - Yg    -> ytflag[tt]        (16-count rendezvous per m-tile)
// Out phase: block (tt,h) computes out[tt*64..+63][h*64..+63], K=1024,
// staging Yg + W_out (f32->bf16 in regs) through reused LDS.
__global__ __launch_bounds__(256, 2) void k_main(
    const float* __restrict__ inp,
    const float* __restrict__ W_XBC,  const float* __restrict__ b_XBC,
    const float* __restrict__ W_gate, const float* __restrict__ b_gate,
    const float* __restrict__ W_logA, const float* __restrict__ b_logA,
    const float* __restrict__ Wout,   const float* __restrict__ bout,
    u32* __restrict__ flags, u32* __restrict__ ytflag,
    float* __restrict__ decArr, float* __restrict__ G,
    u16* __restrict__ Yg, float* __restrict__ out)
{
  const int tt = blockIdx.x, h = blockIdx.y;
  const int tid = threadIdx.x;
  const int w = tid >> 6, l = tid & 63, q = l >> 4, lr = l & 15;
  const int m0 = tt * 64;              // global token row (b*1024 + tl0)
  const int b = tt >> 4;
  const int bh = b * 16 + h;
  const int it = tt & 15;              // chunk index within batch

  __shared__ u16 Xt[64][72];           // input [t][c]; B [t][n]; Hpre; Y-tile
  __shared__ u16 Wt[256][72];          // weights; X^T/B^T|S/C/gate; W-tile
  __shared__ float wl[64];             // W_logA row; then dec[j] in lookback
  __shared__ float sg[64];
  __shared__ float ref_[64], cef[64];

  if (tid < 64) wl[tid] = W_logA[h * 64 + tid];
#pragma unroll
  for (int i = 0; i < 4; ++i) {
    int f = tid + 256 * i; int r = f >> 4, cq = f & 15;
    float4 xv = *(const float4*)(inp + (size_t)(m0 + r) * 1024 + h * 64 + 4 * cq);
    *(ushort4*)&Xt[r][4 * cq] = f2bf4(xv);
  }
#pragma unroll
  for (int i = 0; i < 16; ++i) {       // weights (inline f32->bf16)
    int f = tid + 256 * i; int r = f >> 4, cq = f & 15;
    const float* ws = (r < 192) ? (W_XBC + ((size_t)h * 192 + r) * 64)
                                : (W_gate + ((size_t)h * 64 + (r - 192)) * 64);
    *(ushort4*)&Wt[r][4 * cq] = f2bf4(*(const float4*)(ws + 4 * cq));
  }
  __syncthreads();

  {
    bf16x8 af[4][2];
#pragma unroll
    for (int rt = 0; rt < 4; ++rt) {
      af[rt][0] = *(const bf16x8*)&Xt[16 * rt + lr][q * 8];
      af[rt][1] = *(const bf16x8*)&Xt[16 * rt + lr][32 + q * 8];
    }

    f32x4 acc[4][4];
#pragma unroll
    for (int rt = 0; rt < 4; ++rt)
#pragma unroll
      for (int ct = 0; ct < 4; ++ct) acc[rt][ct] = (f32x4){0.f, 0.f, 0.f, 0.f};

#pragma unroll
    for (int ct = 0; ct < 4; ++ct) {
      bf16x8 b0 = *(const bf16x8*)&Wt[64 * w + 16 * ct + lr][q * 8];
      bf16x8 b1 = *(const bf16x8*)&Wt[64 * w + 16 * ct + lr][32 + q * 8];
#pragma unroll
      for (int rt = 0; rt < 4; ++rt) {
        acc[rt][ct] = __builtin_amdgcn_mfma_f32_16x16x32_bf16(af[rt][0], b0, acc[rt][ct], 0, 0, 0);
        acc[rt][ct] = __builtin_amdgcn_mfma_f32_16x16x32_bf16(af[rt][1], b1, acc[rt][ct], 0, 0, 0);
      }
    }

    // ---- local logA + 64-token inclusive scan (wave 0) ----
    if (tid < 64) {
      float a = b_logA[h];
#pragma unroll 16
      for (int k = 0; k < 64; ++k) a += bfs(Xt[tid][k]) * wl[k];
      float lv = a;
#pragma unroll
      for (int off = 1; off < 64; off <<= 1) {
        float n = __shfl_up(lv, off, 64);
        if (tid >= off) lv += n;
      }
      float L = __shfl(lv, 63, 64);
      sg[tid]   = __expf(L - lv);
      ref_[tid] = __expf(lv);
      cef[tid]  = __expf(-lv);
      if (tid == 63)
        __hip_atomic_store(&decArr[bh * 16 + it], __expf(L),
                           __ATOMIC_RELAXED, __HIP_MEMORY_SCOPE_AGENT);
    }

    // ---- bias + activation in registers ----
    if (w < 3) {
#pragma unroll
      for (int ct = 0; ct < 4; ++ct) {
        float bias = b_XBC[h * 192 + 64 * w + 16 * ct + lr];
#pragma unroll
        for (int rt = 0; rt < 4; ++rt)
#pragma unroll
          for (int r = 0; r < 4; ++r) {
            float s = acc[rt][ct][r] + bias;
            acc[rt][ct][r] = s / (1.f + __expf(-s));
          }
      }
    } else {
#pragma unroll
      for (int ct = 0; ct < 4; ++ct) {
        float bias = b_gate[h * 64 + 16 * ct + lr];
#pragma unroll
        for (int rt = 0; rt < 4; ++rt)
#pragma unroll
          for (int r = 0; r < 4; ++r) acc[rt][ct][r] += bias;
      }
    }
    __syncthreads();   // Wt frags + Xt (scan) consumed

    // ---- transpose into LDS ----
    // w==0: X^T [c][t] -> Wt 0..63 ; w==1: B^T [n][t] -> Wt 64..127, B [t][n]
    // -> Xt ; w==2: C [t][n] -> Wt 128..191 ; w==3: gate [t][c] -> Wt 192..255
#pragma unroll
    for (int ct = 0; ct < 4; ++ct)
#pragma unroll
      for (int rt = 0; rt < 4; ++rt)
#pragma unroll
        for (int r = 0; r < 4; ++r) {
          int t = 16 * rt + 4 * q + r, n = 16 * ct + lr;
          u16 v = f2bf(acc[rt][ct][r]);
          if (w == 0) {
            Wt[n][t] = v;
          } else if (w == 1) {
            Wt[64 + n][t] = v;
            Xt[t][n] = v;
          } else if (w == 2) {
            Wt[128 + t][n] = v;
          } else {
            Wt[192 + t][n] = v;
          }
        }
    __syncthreads();

    // ---- chunk state G[c][n] = sum_t X[t][c]*sg[t]*B[t][n]; publish ----
    {
      bf16x8 a0r = *(const bf16x8*)&Wt[16 * w + lr][q * 8];
      bf16x8 a1r = *(const bf16x8*)&Wt[16 * w + lr][32 + q * 8];
      bf16x8 a0, a1;
#pragma unroll
      for (int jj = 0; jj < 8; ++jj) {
        a0[jj] = (short)f2bf(bfs((u16)a0r[jj]) * sg[q * 8 + jj]);
        a1[jj] = (short)f2bf(bfs((u16)a1r[jj]) * sg[32 + q * 8 + jj]);
      }
      f32x4 gacc[4];
#pragma unroll
      for (int nt = 0; nt < 4; ++nt) {
        gacc[nt] = (f32x4){0.f, 0.f, 0.f, 0.f};
        bf16x8 bb0 = *(const bf16x8*)&Wt[64 + 16 * nt + lr][q * 8];
        bf16x8 bb1 = *(const bf16x8*)&Wt[64 + 16 * nt + lr][32 + q * 8];
        gacc[nt] = __builtin_amdgcn_mfma_f32_16x16x32_bf16(a0, bb0, gacc[nt], 0, 0, 0);
        gacc[nt] = __builtin_amdgcn_mfma_f32_16x16x32_bf16(a1, bb1, gacc[nt], 0, 0, 0);
      }
      float* Gt = G + ((size_t)bh * 16 + it) * 4096;
#pragma unroll
      for (int nt = 0; nt < 4; ++nt)
#pragma unroll
        for (int r = 0; r < 4; ++r)
          __hip_atomic_store(&Gt[(16 * w + 4 * q + r) * 64 + 16 * nt + lr],
                             gacc[nt][r], __ATOMIC_RELAXED,
                             __HIP_MEMORY_SCOPE_AGENT);
    }
  }

  __syncthreads();   // drains vmcnt per wave -> all G/dec atomics completed
  if (tid == 0)
    __hip_atomic_store(&flags[bh * 16 + it], 1u,
                       __ATOMIC_RELEASE, __HIP_MEMORY_SCOPE_AGENT);

  // ================= decoupled lookback: Hpre for this chunk ==============
  float hreg[16];
#pragma unroll
  for (int k = 0; k < 16; ++k) hreg[k] = 0.f;

  if (it > 0) {
    if (tid < it) {
      while (__hip_atomic_load(&flags[bh * 16 + tid],
                               __ATOMIC_ACQUIRE, __HIP_MEMORY_SCOPE_AGENT) == 0u)
        __builtin_amdgcn_s_sleep(2);
      wl[tid] = __hip_atomic_load(&decArr[bh * 16 + tid],
                                  __ATOMIC_RELAXED, __HIP_MEMORY_SCOPE_AGENT);
    }
    __syncthreads();

    const float* Gb = G + (size_t)bh * 16 * 4096 + tid * 16;
    for (int j = 0; j < it; ++j) {
      const f32x4* Gj = (const f32x4*)(Gb + (size_t)j * 4096);
      f32x4 g0 = Gj[0];
      f32x4 g1 = Gj[1];
      f32x4 g2 = Gj[2];
      f32x4 g3 = Gj[3];
      float dj = wl[j];
      hreg[0]  = dj * hreg[0]  + g0[0]; hreg[1]  = dj * hreg[1]  + g0[1];
      hreg[2]  = dj * hreg[2]  + g0[2]; hreg[3]  = dj * hreg[3]  + g0[3];
      hreg[4]  = dj * hreg[4]  + g1[0]; hreg[5]  = dj * hreg[5]  + g1[1];
      hreg[6]  = dj * hreg[6]  + g1[2]; hreg[7]  = dj * hreg[7]  + g1[3];
      hreg[8]  = dj * hreg[8]  + g2[0]; hreg[9]  = dj * hreg[9]  + g2[1];
      hreg[10] = dj * hreg[10] + g2[2]; hreg[11] = dj * hreg[11] + g2[3];
      hreg[12] = dj * hreg[12] + g3[0]; hreg[13] = dj * hreg[13] + g3[1];
      hreg[14] = dj * hreg[14] + g3[2]; hreg[15] = dj * hreg[15] + g3[3];
    }
  }

  // ================= ssm: diagonal quadratic + C·Hpre =====================
  {
    u16 (*Xts)[72] = (u16 (*)[72])&Wt[0];     // X^T [c][t]
    u16 (*Sts)[72] = (u16 (*)[72])&Wt[64];    // overwrite dead B^T
    u16 (*Cts)[72] = (u16 (*)[72])&Wt[128];   // C [t][n]
    u16 (*Gts)[72] = (u16 (*)[72])&Wt[192];   // gate [t][c]

    bf16x8 ca0 = *(const bf16x8*)&Cts[16 * w + lr][q * 8];
    bf16x8 ca1 = *(const bf16x8*)&Cts[16 * w + lr][32 + q * 8];

    // S = tril(ref_i * (C·B^T)_ij * cef_j)  -- B read from Xt (last use)
#pragma unroll
    for (int ct = 0; ct < 4; ++ct) {
      f32x4 s = (f32x4){0.f, 0.f, 0.f, 0.f};
      bf16x8 b0 = *(const bf16x8*)&Xt[16 * ct + lr][q * 8];    // B [t][n]
      bf16x8 b1 = *(const bf16x8*)&Xt[16 * ct + lr][32 + q * 8];
      s = __builtin_amdgcn_mfma_f32_16x16x32_bf16(ca0, b0, s, 0, 0, 0);
      s = __builtin_amdgcn_mfma_f32_16x16x32_bf16(ca1, b1, s, 0, 0, 0);
      int jl = 16 * ct + lr;
      float cj = cef[jl];
#pragma unroll
      for (int r = 0; r < 4; ++r) {
        int il = 16 * w + q * 4 + r;
        float v = (jl > il) ? 0.f : s[r] * ref_[il] * cj;
        Sts[il][jl] = f2bf(v);
      }
    }
    __syncthreads();   // Xt (B) fully consumed -> stash Hpre into Xt

    // Hpre [c][n] <- bf16(hreg): thread covers row c=tid>>2, cols (tid&3)*16..
    {
      int c = tid >> 2, n0 = (tid & 3) * 16;
#pragma unroll
      for (int g4 = 0; g4 < 4; ++g4) {
        ushort4 hv;
        hv.x = f2bf(hreg[4 * g4 + 0]); hv.y = f2bf(hreg[4 * g4 + 1]);
        hv.z = f2bf(hreg[4 * g4 + 2]); hv.w = f2bf(hreg[4 * g4 + 3]);
        *(ushort4*)&Xt[c][n0 + 4 * g4] = hv;
      }
    }
    __syncthreads();

    // Y = S·X_diag + diag(lexp)·(C·Hpre)
    bf16x8 sa0 = *(const bf16x8*)&Sts[16 * w + lr][q * 8];
    bf16x8 sa1 = *(const bf16x8*)&Sts[16 * w + lr][32 + q * 8];
    f32x4 accd[4], acco[4];
#pragma unroll
    for (int ct = 0; ct < 4; ++ct) {
      accd[ct] = (f32x4){0.f, 0.f, 0.f, 0.f};
      acco[ct] = (f32x4){0.f, 0.f, 0.f, 0.f};
      bf16x8 x0 = *(const bf16x8*)&Xts[16 * ct + lr][q * 8];
      bf16x8 x1 = *(const bf16x8*)&Xts[16 * ct + lr][32 + q * 8];
      accd[ct] = __builtin_amdgcn_mfma_f32_16x16x32_bf16(sa0, x0, accd[ct], 0, 0, 0);
      accd[ct] = __builtin_amdgcn_mfma_f32_16x16x32_bf16(sa1, x1, accd[ct], 0, 0, 0);
      bf16x8 h0 = *(const bf16x8*)&Xt[16 * ct + lr][q * 8];    // Hpre [c][n]
      bf16x8 h1 = *(const bf16x8*)&Xt[16 * ct + lr][32 + q * 8];
      acco[ct] = __builtin_amdgcn_mfma_f32_16x16x32_bf16(ca0, h0, acco[ct], 0, 0, 0);
      acco[ct] = __builtin_amdgcn_mfma_f32_16x16x32_bf16(ca1, h1, acco[ct], 0, 0, 0);
    }

    __syncthreads();   // all LDS reads done -> reuse Xts rows as Y [t][c]

#pragma unroll
    for (int ct = 0; ct < 4; ++ct) {
      int c = 16 * ct + lr;
#pragma unroll
      for (int r = 0; r < 4; ++r) {
        int il = 16 * w + q * 4 + r;
        float y = accd[ct][r] + ref_[il] * acco[ct][r];
        Xts[il][c] = f2bf(y);
      }
    }
    __syncthreads();

    // publish gated Yg via packed agent-scope atomic u32 stores
#pragma unroll
    for (int i = 0; i < 4; ++i) {
      int f = tid + 256 * i; int r = f >> 4, cq = f & 15;
      ushort4 yv = *(ushort4*)&Xts[r][4 * cq];
      ushort4 gv = *(ushort4*)&Gts[r][4 * cq];
      u32 lo = (u32)f2bf(bfs(yv.x) * bfs(gv.x))
             | ((u32)f2bf(bfs(yv.y) * bfs(gv.y)) << 16);
      u32 hi = (u32)f2bf(bfs(yv.z) * bfs(gv.z))
             | ((u32)f2bf(bfs(yv.w) * bfs(gv.w)) << 16);
      u32* dst = (u32*)(Yg + (size_t)(m0 + r) * 1024 + h * 64 + 4 * cq);
      __hip_atomic_store(dst + 0, lo, __ATOMIC_RELAXED, __HIP_MEMORY_SCOPE_AGENT);
      __hip_atomic_store(dst + 1, hi, __ATOMIC_RELAXED, __HIP_MEMORY_SCOPE_AGENT);
    }
  }

  __syncthreads();   // drains vmcnt -> Yg publishes complete
  if (tid == 0)
    __hip_atomic_fetch_add(&ytflag[tt], 1u,
                           __ATOMIC_ACQ_REL, __HIP_MEMORY_SCOPE_AGENT);

  // ================= out phase: out[m0..+63][d0..+63], K=1024 =============
  {
    const int d0 = h * 64;
    u16 (*Yt)[72]  = Xt;                    // Y-tile  [64][72]
    u16 (*Wtt)[72] = (u16 (*)[72])&Wt[0];   // W-tile  [64][72]

    // W prefetch (input array, always valid) issued before the flag wait
    float4 pwf[4];
#pragma unroll
    for (int i = 0; i < 4; ++i) {
      int f = tid + 256 * i; int r = f >> 4, cq = f & 15;
      pwf[i] = *(const float4*)(Wout + (size_t)(d0 + r) * 1024 + 4 * cq);
    }

    if (tid == 0) {
      while (__hip_atomic_load(&ytflag[tt],
                               __ATOMIC_ACQUIRE, __HIP_MEMORY_SCOPE_AGENT) < 16u)
        __builtin_amdgcn_s_sleep(2);
    }
    __syncthreads();   // Yg rows m0..m0+63 fully published

    f32x4 oacc[4];
#pragma unroll
    for (int ct = 0; ct < 4; ++ct) oacc[ct] = (f32x4){0.f, 0.f, 0.f, 0.f};

    ushort4 py[4];
#pragma unroll
    for (int i = 0; i < 4; ++i) {
      int f = tid + 256 * i; int r = f >> 4, cq = f & 15;
      py[i] = *(const ushort4*)(Yg + (size_t)(m0 + r) * 1024 + 4 * cq);
    }

    for (int kt = 0; kt < 16; ++kt) {
      __syncthreads();
#pragma unroll
      for (int i = 0; i < 4; ++i) {
        int f = tid + 256 * i; int r = f >> 4, cq = f & 15;
        *(ushort4*)&Yt[r][4 * cq]  = py[i];
        *(ushort4*)&Wtt[r][4 * cq] = f2bf4(pwf[i]);
      }
      __syncthreads();

      if (kt < 15) {
        int k1 = (kt + 1) * 64;
#pragma unroll
        for (int i = 0; i < 4; ++i) {
          int f = tid + 256 * i; int r = f >> 4, cq = f & 15;
          py[i]  = *(const ushort4*)(Yg + (size_t)(m0 + r) * 1024 + k1 + 4 * cq);
          pwf[i] = *(const float4*)(Wout + (size_t)(d0 + r) * 1024 + k1 + 4 * cq);
        }
      }

      bf16x8 a0 = *(const bf16x8*)&Yt[16 * w + lr][q * 8];
      bf16x8 a1 = *(const bf16x8*)&Yt[16 * w + lr][32 + q * 8];
#pragma unroll
      for (int ct = 0; ct < 4; ++ct) {
        bf16x8 b0 = *(const bf16x8*)&Wtt[16 * ct + lr][q * 8];
        bf16x8 b1 = *(const bf16x8*)&Wtt[16 * ct + lr][32 + q * 8];
        oacc[ct] = __builtin_amdgcn_mfma_f32_16x16x32_bf16(a0, b0, oacc[ct], 0, 0, 0);
        oacc[ct] = __builtin_amdgcn_mfma_f32_16x16x32_bf16(a1, b1, oacc[ct], 0, 0, 0);
      }
    }

#pragma unroll
    for (int ct = 0; ct < 4; ++ct) {
      int d = d0 + 16 * ct + lr;
      float bo = bout[d];
#pragma unroll
      for (int r = 0; r < 4; ++r) {
        int m = m0 + 16 * w + q * 4 + r;
        out[(size_t)m * 1024 + d] = oacc[ct][r] + bo;
      }
    }
  }
}

// ---------------- host launcher ----------------
extern "C" void kernel_launch(void* const* d_in, const int* in_sizes, int n_in,
                              void* d_out, int out_size, void* d_ws, size_t ws_size,
                              hipStream_t stream)
{
  const float* inp   = (const float*)d_in[0];
  const float* WlogA = (const float*)d_in[1];
  const float* blogA = (const float*)d_in[2];
  const float* WXBC  = (const float*)d_in[3];
  const float* bXBC  = (const float*)d_in[4];
  const float* Wgate = (const float*)d_in[5];
  const float* bgate = (const float*)d_in[6];
  const float* Wout  = (const float*)d_in[7];
  const float* bout  = (const float*)d_in[8];
  float* out = (float*)d_out;

  u32*   flags  = (u32*)d_ws;                          // 512 u32 @ 0
  u32*   ytflag = (u32*)((char*)d_ws + 2048);          // 32 u32 @ 2048
  float* decA   = (float*)((char*)d_ws + 4096);        // 512 f32
  float* G      = decA + 512;                          // 32*16*4096 f32 = 8 MiB
  u16*   Yg     = (u16*)(G + (size_t)32 * 16 * 4096);  // 2M u16 = 4 MiB

  (void)hipMemsetAsync(d_ws, 0, 4096, stream);         // reset flags + ytflag

  k_main<<<dim3(32, 16, 1), dim3(256, 1, 1), 0, stream>>>(
      inp, WXBC, bXBC, Wgate, bgate, WlogA, blogA, Wout, bout,
      flags, ytflag, decA, G, Yg, out);
}